// Round 3
// baseline (123.766 us; speedup 1.0000x reference)
//
#include <hip/hip_runtime.h>
#include <math.h>

#define NB 8
#define NQ 256
#define NK 256
#define DIN 10
#define FDIM 64
#define HIDDEN 256
#define NH 8
#define ROWS_PER_BLK 4

#define FSTRIDE 64    // shorts per feat row; XOR-swizzled 8-short col-blocks
#define HSTRIDE 264   // shorts per h row (256 + 8 pad) -> 528 B

typedef float f32x4 __attribute__((ext_vector_type(4)));
typedef short bf16x8 __attribute__((ext_vector_type(8)));

__device__ __forceinline__ short f2bf(float f) {
    return (short)((__float_as_uint(f) + 0x8000u) >> 16);
}
// pack two floats -> two bf16 in ONE instr (RTNE). a -> low half, b -> high.
__device__ __forceinline__ unsigned cvtpk(float a, float b) {
    unsigned r;
    asm("v_cvt_pk_bf16_f32 %0, %1, %2" : "=v"(r) : "v"(a), "v"(b));
    return r;
}
__device__ __forceinline__ float rcpf(float x)  { return __builtin_amdgcn_rcpf(x); }
__device__ __forceinline__ float ex2f(float x)  { return __builtin_amdgcn_exp2f(x); }
__device__ __forceinline__ float sqtf(float x)  { return __builtin_amdgcn_sqrtf(x); }

__device__ __forceinline__ void four4(float x, float* dst) {
    float s1 = __sinf(x), c1 = __cosf(x);
    float s2 = 2.f * s1 * c1, c2 = 1.f - 2.f * s1 * s1;
    float s4 = 2.f * s2 * c2, c4 = 1.f - 2.f * s2 * s2;
    float s8 = 2.f * s4 * c4, c8 = 1.f - 2.f * s4 * s4;
    dst[0] = s1; dst[1] = s2; dst[2] = s4; dst[3] = s8;
    dst[4] = c1; dst[5] = c2; dst[6] = c4; dst[7] = c8;
}
__device__ __forceinline__ void four2(float x, float* dst) {
    float s1 = __sinf(x), c1 = __cosf(x);
    dst[0] = s1; dst[1] = 2.f * s1 * c1;
    dst[2] = c1; dst[3] = 1.f - 2.f * s1 * s1;
}

// Block = one (b, i0..i0+3): FOUR query rows, 256 pairs each; EIGHT waves.
// Grid = 512 = 2 blocks/CU -> 16 waves/CU. LDS 66560 B.
// r3: phase-overlap restructure (r2 showed phase-serialization, not issue
// count, is the wall):
//   - GEMM2 pipelined one chunk behind, interleaved with silu(c) in the
//     same basic block (MFMA+LDS overlap trans). Epilogue flush.
//   - feature phase folded into chunk-3: compute(r+1)->regs during chunks,
//     store to feat_s between B1/B2 of chunk 3. Row-0 prologue only.
//   - bias as MFMA C-in (no acc-init movs).
//   - rcp/sqrt/tanh via raw instrs (no div-fixup chains).
// Scale folds unchanged: W1,b1 pre-scaled by -log2(e); W2 by -ln(2).
__global__ __launch_bounds__(512, 4) void relfeat_mfma_kernel(
    const float* __restrict__ q, const float* __restrict__ k,
    const float* __restrict__ W1, const float* __restrict__ b1,
    const float* __restrict__ W2, const float* __restrict__ b2,
    float* __restrict__ out)
{
    __shared__ __align__(16) short feat_s[NK * FSTRIDE];   // 32768 B
    __shared__ __align__(16) short h_s[64 * HSTRIDE];      // 33792 B

    const int t = threadIdx.x;          // 0..511
    const int wave = t >> 6;            // 0..7
    const int lane15 = t & 15;
    const int quad = (t >> 4) & 3;
    const int p = t & 255;              // pair id for features / staging
    const int half = t >> 8;            // 0/1: which half of features
    const int b = blockIdx.x >> 6;
    const int i0 = (blockIdx.x & 63) * ROWS_PER_BLK;

    // ---- k-row for pair j = p: block-invariant, cache in regs ----
    const float* kp = k + ((size_t)b * NK + p) * DIN;
    const float k0 = kp[0], k3 = kp[3], k4 = kp[4], k5 = kp[5], k6 = kp[6],
                k7 = kp[7], k8 = kp[8];
    const float k_speed = sqtf(k5 * k5 + k6 * k6);   // row-invariant

    // ---- W2 fragments in regs (GEMM2 B-operand), scaled by -ln2 ----
    bf16x8 w2f[8];
    if (wave < 4) {
#pragma unroll
        for (int ks = 0; ks < 8; ++ks) {
            const float* wp = W2 + (size_t)(ks * 32 + quad * 8) * NH + (lane15 & 7);
            bf16x8 v;
#pragma unroll
            for (int e = 0; e < 8; ++e)
                v[e] = f2bf(-0.69314718f * wp[(size_t)e * NH]);
            w2f[ks] = v;
        }
    }

    // ---- W1 fragments (A operand), scaled by -log2e ----
    const int n0 = wave * 32;
    bf16x8 w1f[2][2];
#pragma unroll
    for (int nt = 0; nt < 2; ++nt)
#pragma unroll
        for (int ks = 0; ks < 2; ++ks) {
            const float* wp = W1 + (size_t)(ks * 32 + quad * 8) * HIDDEN
                              + (n0 + nt * 16 + lane15);
            bf16x8 v;
#pragma unroll
            for (int e = 0; e < 8; ++e)
                v[e] = f2bf(-1.44269504f * wp[(size_t)e * HIDDEN]);
            w1f[nt][ks] = v;
        }
    // bias fragment (MFMA C-in for ks=0), scaled by -log2e
    f32x4 b1c[2];
#pragma unroll
    for (int nt = 0; nt < 2; ++nt) {
        float4 bb = *(const float4*)&b1[n0 + nt * 16 + quad * 4];
        b1c[nt] = (f32x4){-1.44269504f * bb.x, -1.44269504f * bb.y,
                          -1.44269504f * bb.z, -1.44269504f * bb.w};
    }
    const float b2v = (lane15 < NH) ? b2[lane15] : 0.f;

    const int sw = p & 7;        // feature-store swizzle
    const int swr = lane15 & 7;  // feat B-frag read swizzle

    // ---- feature compute (pair p, row irow) -> 4 packed uint4 ----
    auto feat_compute = [&](int irow, uint4* fr) {
        const float* qp = q + ((size_t)b * NQ + irow) * DIN;
        const float q0 = qp[0], q3 = qp[3], q4 = qp[4], q5 = qp[5],
                    q6 = qp[6], q7 = qp[7], q8 = qp[8];
        const float dpx = k3 - q3, dpy = k4 - q4;
        const float dvx = k5 - q5, dvy = k6 - q6;
        const float dist = sqtf(dpx * dpx + dpy * dpy + 1e-6f);
        float feat[32];
        if (half == 0) {
            // c8 {0,1,6,7}: dist4 | inv_dist4 | ttca2+dist2 | team2+dspeed2
            const float inv_dist = rcpf(dist + 0.1f);
            const float dot_dp_dv = dpx * dvx + dpy * dvy;
            const float speed_sq = dvx * dvx + dvy * dvy;
            // tanh(relu(z)) = 1 - 2/(1+2^(2*log2e*z)), z>=0
            const float z = fmaxf(0.f, -dot_dp_dv * rcpf(speed_sq + 1e-6f));
            const float ttca = 1.f - 2.f * rcpf(1.f + ex2f(2.88539008f * z));
            const float q_speed = sqtf(q5 * q5 + q6 * q6);
            const float delta_speed = k_speed - q_speed;
            four4(dist,     feat + 0);
            four4(inv_dist, feat + 8);
            four2(ttca,     feat + 16);
            feat[20] = feat[0]; feat[21] = feat[1];   // four2(dist) reuse
            feat[22] = feat[4]; feat[23] = feat[5];
            const bool st = (q0 == k0);               // same_team constants
            feat[24] = st ? 0.84147098f : 0.f;
            feat[25] = st ? 0.90929743f : 0.f;
            feat[26] = st ? 0.54030231f : 1.f;
            feat[27] = st ? -0.41614684f : 1.f;
            four2(delta_speed, feat + 28);
        } else {
            // c8 {2,3,4,5}: ata4 | aspect4 | dpx2+dpy2 | dvx2+dvy2
            const float inv_d2 = rcpf(dist + 1e-6f);
            const float bear_x = dpx * inv_d2, bear_y = dpy * inv_d2;
            const float ata = bear_x * q7 + bear_y * q8;
            const float aspect = bear_x * k7 + bear_y * k8;
            four4(ata,    feat + 0);
            four4(aspect, feat + 8);
            four2(dpx,    feat + 16);
            four2(dpy,    feat + 20);
            four2(dvx,    feat + 24);
            four2(dvy,    feat + 28);
        }
#pragma unroll
        for (int j = 0; j < 4; ++j) {
            fr[j].x = cvtpk(feat[j * 8 + 0], feat[j * 8 + 1]);
            fr[j].y = cvtpk(feat[j * 8 + 2], feat[j * 8 + 3]);
            fr[j].z = cvtpk(feat[j * 8 + 4], feat[j * 8 + 5]);
            fr[j].w = cvtpk(feat[j * 8 + 6], feat[j * 8 + 7]);
        }
    };
    auto feat_store = [&](const uint4* fr) {
#pragma unroll
        for (int j = 0; j < 4; ++j) {
            const int c8 = half ? (j + 2) : (j < 2 ? j : j + 4);
            *(uint4*)&feat_s[p * FSTRIDE + ((c8 ^ sw) * 8)] = fr[j];
        }
    };
    // silu (scale-folded): acc -> packed bf16 pairs (regs only, no LDS)
    auto silu_pk = [&](const f32x4 (&acc)[2][4], uint2 (&pk)[2][4]) {
#pragma unroll
        for (int nt = 0; nt < 2; ++nt)
#pragma unroll
            for (int mt = 0; mt < 4; ++mt) {
                float s[4];
#pragma unroll
                for (int r = 0; r < 4; ++r) {
                    const float a = acc[nt][mt][r];     // = -log2e * preact
                    const float e = ex2f(a);
                    s[r] = a * rcpf(1.f + e);           // -1.4427*silu
                }
                pk[nt][mt].x = cvtpk(s[0], s[1]);
                pk[nt][mt].y = cvtpk(s[2], s[3]);
            }
    };
    // GEMM2 for a PENDING chunk (h_s holds its data); wave<4 only.
    auto gemm2 = [&](int oi, int op0) {
        const int pw = wave * 16;
        f32x4 acc2 = (f32x4){b2v, b2v, b2v, b2v};
#pragma unroll
        for (int ks = 0; ks < 8; ++ks) {
            const bf16x8 ha = *(const bf16x8*)&h_s[(pw + lane15) * HSTRIDE
                                                    + ks * 32 + quad * 8];
            acc2 = __builtin_amdgcn_mfma_f32_16x16x32_bf16(ha, w2f[ks], acc2, 0, 0, 0);
        }
        if (lane15 < NH) {
            float* op = out + (((size_t)b * NH + lane15) * NQ + oi) * NK
                        + (op0 + pw + quad * 4);
            *(float4*)op = make_float4(acc2[0], acc2[1], acc2[2], acc2[3]);
        }
    };

    // ---- prologue: features(row 0) ----
    {
        uint4 fr[4];
        feat_compute(i0, fr);
        feat_store(fr);
    }
    __syncthreads();   // feat_s(row 0) ready

    int pend_i = -1, pend_p0 = 0;   // chunk whose GEMM2 is still owed

    // ================= row loop =================
#pragma unroll 1
    for (int row = 0; row < ROWS_PER_BLK; ++row) {
        const int i = i0 + row;
#pragma unroll 1
        for (int c = 0; c < 4; ++c) {
            const int p0 = c * 64;

            // GEMM1': bias rides as C-in on the ks=0 MFMAs
            f32x4 acc[2][4];
#pragma unroll
            for (int mt = 0; mt < 4; ++mt) {
                const int r2 = p0 + mt * 16 + lane15;
                const bf16x8 fb = *(const bf16x8*)
                    &feat_s[r2 * FSTRIDE + ((quad ^ swr) * 8)];
                acc[0][mt] = __builtin_amdgcn_mfma_f32_16x16x32_bf16(
                    w1f[0][0], fb, b1c[0], 0, 0, 0);
                acc[1][mt] = __builtin_amdgcn_mfma_f32_16x16x32_bf16(
                    w1f[1][0], fb, b1c[1], 0, 0, 0);
            }
#pragma unroll
            for (int mt = 0; mt < 4; ++mt) {
                const int r2 = p0 + mt * 16 + lane15;
                const bf16x8 fb = *(const bf16x8*)
                    &feat_s[r2 * FSTRIDE + (((4 + quad) ^ swr) * 8)];
#pragma unroll
                for (int nt = 0; nt < 2; ++nt)
                    acc[nt][mt] = __builtin_amdgcn_mfma_f32_16x16x32_bf16(
                        w1f[nt][1], fb, acc[nt][mt], 0, 0, 0);
            }

            // silu(c) [+ pending GEMM2 interleaved, waves 0-3]
            uint2 pk[2][4];
            if (wave < 4 && pend_i >= 0) {
                silu_pk(acc, pk);           // trans pipe
                gemm2(pend_i, pend_p0);     // MFMA + LDS, same block: overlap
            } else {
                silu_pk(acc, pk);
            }

            // features(row+1) -> regs during last chunk (off the serial path)
            uint4 fr[4];
            if (c == 3 && row + 1 < ROWS_PER_BLK)
                feat_compute(i + 1, fr);

            __syncthreads();  // B1: h_s(pend) readers + feat_s(row) readers done

#pragma unroll
            for (int nt = 0; nt < 2; ++nt)
#pragma unroll
                for (int mt = 0; mt < 4; ++mt) {
                    const int pair = mt * 16 + lane15;
                    const int hbase = n0 + nt * 16 + quad * 4;
                    *(uint2*)&h_s[pair * HSTRIDE + hbase] = pk[nt][mt];
                }
            if (c == 3 && row + 1 < ROWS_PER_BLK)
                feat_store(fr);             // feat_s(row+1), guarded by B1/B2

            __syncthreads();  // B2: h_s(c) [+ feat_s(row+1)] ready

            pend_i = i; pend_p0 = p0;
        }
    }
    // ---- epilogue: flush last pending GEMM2 ----
    if (wave < 4)
        gemm2(pend_i, pend_p0);
}

extern "C" void kernel_launch(void* const* d_in, const int* in_sizes, int n_in,
                              void* d_out, int out_size, void* d_ws, size_t ws_size,
                              hipStream_t stream) {
    const float* q  = (const float*)d_in[0];
    const float* k  = (const float*)d_in[1];
    const float* W1 = (const float*)d_in[2];
    const float* b1 = (const float*)d_in[3];
    const float* W2 = (const float*)d_in[4];
    const float* b2 = (const float*)d_in[5];
    float* out = (float*)d_out;

    dim3 grid(NB * NQ / ROWS_PER_BLK);  // 512 blocks = 2/CU, one dispatch round
    dim3 block(512);                    // 8 waves: 16 waves/CU resident
    relfeat_mfma_kernel<<<grid, block, 0, stream>>>(q, k, W1, b1, W2, b2, out);
}

// Round 4
// 121.918 us; speedup vs baseline: 1.0152x; 1.0152x over previous
//
#include <hip/hip_runtime.h>
#include <math.h>

#define NB 8
#define NQ 256
#define NK 256
#define DIN 10
#define FDIM 64
#define HIDDEN 256
#define NH 8
#define ROWS_PER_BLK 8

#define FSTRIDE 64    // shorts per feat row; XOR-swizzled 8-short col-blocks
#define HSTRIDE 264   // shorts per h row (256 + 8 pad) -> 528 B

typedef float f32x4 __attribute__((ext_vector_type(4)));
typedef short bf16x8 __attribute__((ext_vector_type(8)));

__device__ __forceinline__ short f2bf(float f) {
    return (short)((__float_as_uint(f) + 0x8000u) >> 16);
}
// pack two floats -> two bf16 in ONE instr (RTNE). a -> low half, b -> high.
__device__ __forceinline__ unsigned cvtpk(float a, float b) {
    unsigned r;
    asm("v_cvt_pk_bf16_f32 %0, %1, %2" : "=v"(r) : "v"(a), "v"(b));
    return r;
}
__device__ __forceinline__ float rcpf(float x) { return __builtin_amdgcn_rcpf(x); }
__device__ __forceinline__ float ex2f(float x) { return __builtin_amdgcn_exp2f(x); }
__device__ __forceinline__ float sqtf(float x) { return __builtin_amdgcn_sqrtf(x); }

__device__ __forceinline__ void four4(float x, float* dst) {
    float s1 = __sinf(x), c1 = __cosf(x);
    float s2 = 2.f * s1 * c1, c2 = 1.f - 2.f * s1 * s1;
    float s4 = 2.f * s2 * c2, c4 = 1.f - 2.f * s2 * s2;
    float s8 = 2.f * s4 * c4, c8 = 1.f - 2.f * s4 * s4;
    dst[0] = s1; dst[1] = s2; dst[2] = s4; dst[3] = s8;
    dst[4] = c1; dst[5] = c2; dst[6] = c4; dst[7] = c8;
}
__device__ __forceinline__ void four2(float x, float* dst) {
    float s1 = __sinf(x), c1 = __cosf(x);
    dst[0] = s1; dst[1] = 2.f * s1 * c1;
    dst[2] = c1; dst[3] = 1.f - 2.f * s1 * s1;
}

// r4: single-barrier chunks via h ping-pong; 1024 threads, 16 waves, 1 blk/CU.
//   region(c) = { G2(pend) [reads hbuf[pb]] ; G1(c) ; silu ; write hbuf[c&1] ;
//                 barrier }.
//   WAR: write(c)->bufB vs G2(c-2) reads bufB: separated by bar(c-1).
//   RAW: write(c)->bufB vs G2(c) reads bufB: separated by bar(c).
//   Barriers: 5/row (was 9). No arrays live across barriers (r3 spill lesson).
//   G1 re-shard for 16 waves: wave = (hw,pw) in 4x4; 4 hidden-tiles x 1
//   pair-tile each -> only 2 feat fragment reads per wave per chunk
//   (global G1 LDS reads halved). G2: 4 M-tiles on waves 0-3 = one per SIMD.
//   Features: 4 threads/pair (tq = t>>8), serial in feat phase.
// Scale folds: W1,b1 pre-scaled by -log2(e); W2 by -ln(2).
__global__ __launch_bounds__(1024, 4) void relfeat_mfma_kernel(
    const float* __restrict__ q, const float* __restrict__ k,
    const float* __restrict__ W1, const float* __restrict__ b1,
    const float* __restrict__ W2, const float* __restrict__ b2,
    float* __restrict__ out)
{
    __shared__ __align__(16) short feat_s[NK * FSTRIDE];    // 32768 B
    __shared__ __align__(16) short hbuf[2][64 * HSTRIDE];   // 67584 B

    const int t = threadIdx.x;          // 0..1023
    const int lane15 = t & 15;
    const int quad = (t >> 4) & 3;
    const int wave = t >> 6;            // 0..15
    const int hw = wave >> 2;           // hidden group 0..3 (64 hidden each)
    const int pw = wave & 3;            // pair tile 0..3 (16 pairs each)
    const int p = t & 255;              // pair id for features / k-row
    const int tq = t >> 8;              // 0..3: feature quarter (wave-uniform)
    const int b = blockIdx.x >> 5;
    const int i0 = (blockIdx.x & 31) * ROWS_PER_BLK;

    // ---- k-row for pair j = p: block-invariant, cache in regs ----
    const float* kp = k + ((size_t)b * NK + p) * DIN;
    const float k0 = kp[0], k3 = kp[3], k4 = kp[4], k5 = kp[5], k6 = kp[6],
                k7 = kp[7], k8 = kp[8];

    // ---- W2 fragments in regs (GEMM2 B-operand), scaled by -ln2 ----
    bf16x8 w2f[8];
    if (wave < 4) {
#pragma unroll
        for (int ks = 0; ks < 8; ++ks) {
            const float* wp = W2 + (size_t)(ks * 32 + quad * 8) * NH + (lane15 & 7);
            bf16x8 v;
#pragma unroll
            for (int e = 0; e < 8; ++e)
                v[e] = f2bf(-0.69314718f * wp[(size_t)e * NH]);
            w2f[ks] = v;
        }
    }

    // ---- W1 fragments (A operand): 4 hidden-tiles x 2 ks, scaled -log2e ----
    bf16x8 w1f[4][2];
#pragma unroll
    for (int nt = 0; nt < 4; ++nt)
#pragma unroll
        for (int ks = 0; ks < 2; ++ks) {
            const float* wp = W1 + (size_t)(ks * 32 + quad * 8) * HIDDEN
                              + (hw * 64 + nt * 16 + lane15);
            bf16x8 v;
#pragma unroll
            for (int e = 0; e < 8; ++e)
                v[e] = f2bf(-1.44269504f * wp[(size_t)e * HIDDEN]);
            w1f[nt][ks] = v;
        }
    // bias fragment (MFMA C-in at ks=0), scaled by -log2e
    f32x4 b1c[4];
#pragma unroll
    for (int nt = 0; nt < 4; ++nt) {
        float4 bb = *(const float4*)&b1[hw * 64 + nt * 16 + quad * 4];
        b1c[nt] = (f32x4){-1.44269504f * bb.x, -1.44269504f * bb.y,
                          -1.44269504f * bb.z, -1.44269504f * bb.w};
    }
    const float b2v = (lane15 < NH) ? b2[lane15] : 0.f;

    const int sw = p & 7;        // feature-store swizzle
    const int swr = lane15 & 7;  // feat B-frag read swizzle

    // GEMM2 for a pending chunk; waves 0-3 only (one per SIMD).
    auto gemm2 = [&](int oi, int op0, int pb) {
        const short* hb = hbuf[pb];
        f32x4 acc2 = (f32x4){b2v, b2v, b2v, b2v};
#pragma unroll
        for (int ks = 0; ks < 8; ++ks) {
            const bf16x8 ha = *(const bf16x8*)&hb[(wave * 16 + lane15) * HSTRIDE
                                                  + ks * 32 + quad * 8];
            acc2 = __builtin_amdgcn_mfma_f32_16x16x32_bf16(ha, w2f[ks], acc2, 0, 0, 0);
        }
        if (lane15 < NH) {
            float* op = out + (((size_t)b * NH + lane15) * NQ + oi) * NK
                        + (op0 + wave * 16 + quad * 4);
            *(float4*)op = make_float4(acc2[0], acc2[1], acc2[2], acc2[3]);
        }
    };

    int pend_i = -1, pend_p0 = 0, pend_b = 0;

    // ================= row loop: 8 query rows =================
#pragma unroll 1
    for (int row = 0; row < ROWS_PER_BLK; ++row) {
        const int i = i0 + row;

        // ---- features for pair (i, j=p): 4 threads/pair, quarter each ----
        {
            const float* qp = q + ((size_t)b * NQ + i) * DIN;
            const float q3 = qp[3], q4 = qp[4], q5 = qp[5], q6 = qp[6];
            const float dpx = k3 - q3, dpy = k4 - q4;
            const float dvx = k5 - q5, dvy = k6 - q6;
            float f[16];
            if (tq == 0) {
                // c8 0,1: dist4 | inv_dist4
                const float dist = sqtf(dpx * dpx + dpy * dpy + 1e-6f);
                const float inv_dist = rcpf(dist + 0.1f);
                four4(dist,     f);
                four4(inv_dist, f + 8);
            } else if (tq == 1) {
                // c8 2,3: ata4 | aspect4
                const float q7 = qp[7], q8 = qp[8];
                const float dist = sqtf(dpx * dpx + dpy * dpy + 1e-6f);
                const float inv_d2 = rcpf(dist + 1e-6f);
                const float bx = dpx * inv_d2, by = dpy * inv_d2;
                four4(bx * q7 + by * q8, f);
                four4(bx * k7 + by * k8, f + 8);
            } else if (tq == 2) {
                // c8 4,5: dpx2+dpy2 | dvx2+dvy2
                four2(dpx, f);     four2(dpy, f + 4);
                four2(dvx, f + 8); four2(dvy, f + 12);
            } else {
                // c8 6,7: ttca2+dist2 | team2+dspeed2
                const float q0 = qp[0];
                const float dist = sqtf(dpx * dpx + dpy * dpy + 1e-6f);
                const float dd = dpx * dvx + dpy * dvy;
                const float ss = dvx * dvx + dvy * dvy;
                // tanh(relu(z)) = 1 - 2/(1 + 2^(2*log2e*z)), z >= 0
                const float z = fmaxf(0.f, -dd * rcpf(ss + 1e-6f));
                const float ttca = 1.f - 2.f * rcpf(1.f + ex2f(2.88539008f * z));
                four2(ttca, f);
                four2(dist, f + 4);
                const bool st = (qp[0] == k0); (void)q0;
                f[8]  = st ? 0.84147098f : 0.f;     // sin(1)/sin(0)
                f[9]  = st ? 0.90929743f : 0.f;     // sin(2)/sin(0)
                f[10] = st ? 0.54030231f : 1.f;     // cos(1)/cos(0)
                f[11] = st ? -0.41614684f : 1.f;    // cos(2)/cos(0)
                const float qs = sqtf(q5 * q5 + q6 * q6);
                const float ksp = sqtf(k5 * k5 + k6 * k6);
                four2(ksp - qs, f + 12);
            }
#pragma unroll
            for (int j = 0; j < 2; ++j) {
                const int c8 = tq * 2 + j;
                uint4 v;
                v.x = cvtpk(f[j * 8 + 0], f[j * 8 + 1]);
                v.y = cvtpk(f[j * 8 + 2], f[j * 8 + 3]);
                v.z = cvtpk(f[j * 8 + 4], f[j * 8 + 5]);
                v.w = cvtpk(f[j * 8 + 6], f[j * 8 + 7]);
                *(uint4*)&feat_s[p * FSTRIDE + ((c8 ^ sw) * 8)] = v;
            }
        }
        __syncthreads();   // feat_s(row) ready (prev readers done pre-bar(c3))

        // ---- 4 chunks of 64 pairs, ONE barrier each ----
#pragma unroll 1
        for (int c = 0; c < 4; ++c) {
            const int p0 = c * 64;
            const int wb = c & 1;           // write buffer this chunk

            // pending GEMM2 first: reads hbuf[pend_b], data sealed by last bar
            if (wave < 4 && pend_i >= 0)
                gemm2(pend_i, pend_p0, pend_b);

            // GEMM1': wave computes 4 hidden-tiles x 16 pairs; bias as C-in
            const int r2 = p0 + pw * 16 + lane15;
            const bf16x8 fb0 = *(const bf16x8*)
                &feat_s[r2 * FSTRIDE + ((quad ^ swr) * 8)];
            const bf16x8 fb1 = *(const bf16x8*)
                &feat_s[r2 * FSTRIDE + (((4 + quad) ^ swr) * 8)];
            f32x4 acc[4];
#pragma unroll
            for (int nt = 0; nt < 4; ++nt)
                acc[nt] = __builtin_amdgcn_mfma_f32_16x16x32_bf16(
                    w1f[nt][0], fb0, b1c[nt], 0, 0, 0);
#pragma unroll
            for (int nt = 0; nt < 4; ++nt)
                acc[nt] = __builtin_amdgcn_mfma_f32_16x16x32_bf16(
                    w1f[nt][1], fb1, acc[nt], 0, 0, 0);

            // silu (scale-folded) -> pack -> write hbuf[wb]
#pragma unroll
            for (int nt = 0; nt < 4; ++nt) {
                float s[4];
#pragma unroll
                for (int r = 0; r < 4; ++r) {
                    const float a = acc[nt][r];      // = -log2e * preact
                    const float e = ex2f(a);
                    s[r] = a * rcpf(1.f + e);        // -1.4427*silu
                }
                uint2 pk;
                pk.x = cvtpk(s[0], s[1]);
                pk.y = cvtpk(s[2], s[3]);
                *(uint2*)&hbuf[wb][(pw * 16 + lane15) * HSTRIDE
                                   + hw * 64 + nt * 16 + quad * 4] = pk;
            }

            __syncthreads();   // seals hbuf[wb]; releases hbuf[wb^1]

            pend_i = i; pend_p0 = p0; pend_b = wb;
        }
    }
    // ---- epilogue: flush last pending GEMM2 ----
    if (wave < 4)
        gemm2(pend_i, pend_p0, pend_b);
}

extern "C" void kernel_launch(void* const* d_in, const int* in_sizes, int n_in,
                              void* d_out, int out_size, void* d_ws, size_t ws_size,
                              hipStream_t stream) {
    const float* q  = (const float*)d_in[0];
    const float* k  = (const float*)d_in[1];
    const float* W1 = (const float*)d_in[2];
    const float* b1 = (const float*)d_in[3];
    const float* W2 = (const float*)d_in[4];
    const float* b2 = (const float*)d_in[5];
    float* out = (float*)d_out;

    dim3 grid(NB * NQ / ROWS_PER_BLK);  // 256 blocks = exactly 1/CU
    dim3 block(1024);                   // 16 waves: 16 waves/CU resident
    relfeat_mfma_kernel<<<grid, block, 0, stream>>>(q, k, W1, b1, W2, b2, out);
}

// Round 5
// 107.729 us; speedup vs baseline: 1.1489x; 1.1317x over previous
//
#include <hip/hip_runtime.h>
#include <math.h>

#define NB 8
#define NQ 256
#define NK 256
#define DIN 10
#define FDIM 64
#define HIDDEN 256
#define NH 8
#define ROWS_PER_BLK 4

#define FSTRIDE 64    // shorts per feat row; XOR-swizzled 8-short col-blocks
#define HSTRIDE 264   // shorts per h row (256 + 8 pad) -> 528 B

typedef float f32x4 __attribute__((ext_vector_type(4)));
typedef float f32x2 __attribute__((ext_vector_type(2)));
typedef short bf16x8 __attribute__((ext_vector_type(8)));

__device__ __forceinline__ short f2bf(float f) {
    return (short)((__float_as_uint(f) + 0x8000u) >> 16);
}
// pack two floats -> two bf16 in ONE instr (RTNE). a -> low half, b -> high.
__device__ __forceinline__ unsigned cvtpk(float a, float b) {
    unsigned r;
    asm("v_cvt_pk_bf16_f32 %0, %1, %2" : "=v"(r) : "v"(a), "v"(b));
    return r;
}
__device__ __forceinline__ float rcpf(float x) { return __builtin_amdgcn_rcpf(x); }
__device__ __forceinline__ float ex2f(float x) { return __builtin_amdgcn_exp2f(x); }
__device__ __forceinline__ float sqtf(float x) { return __builtin_amdgcn_sqrtf(x); }

__device__ __forceinline__ void four4(float x, float* dst) {
    float s1 = __sinf(x), c1 = __cosf(x);
    float s2 = 2.f * s1 * c1, c2 = 1.f - 2.f * s1 * s1;
    float s4 = 2.f * s2 * c2, c4 = 1.f - 2.f * s2 * s2;
    float s8 = 2.f * s4 * c4, c8 = 1.f - 2.f * s4 * s4;
    dst[0] = s1; dst[1] = s2; dst[2] = s4; dst[3] = s8;
    dst[4] = c1; dst[5] = c2; dst[6] = c4; dst[7] = c8;
}
__device__ __forceinline__ void four2(float x, float* dst) {
    float s1 = __sinf(x), c1 = __cosf(x);
    dst[0] = s1; dst[1] = 2.f * s1 * c1;
    dst[2] = c1; dst[3] = 1.f - 2.f * s1 * s1;
}

// r5 = r2 (best proven, 53.4us dispatch) + spill-free instruction trims ONLY.
// r3/r4 lesson: structural variants spill (FETCH/WRITE balloon) -> keep r2's
// 512-thread / 2-blocks/CU shape and VGPR budget exactly.
//   - bias as MFMA C-in at ks=0 (kills 32 acc-init movs/chunk/thread)
//   - silu add/mul as float2 ext-vector -> v_pk_add_f32/v_pk_mul_f32
//   - feature math on raw rcp/sqrt + exp2-form tanh (no div-fixup chains)
//   - G2 out-pointer hoisted out of chunk loop
// Scale folds unchanged: W1,b1 pre-scaled by -log2(e); W2 by -ln(2).
__global__ __launch_bounds__(512, 4) void relfeat_mfma_kernel(
    const float* __restrict__ q, const float* __restrict__ k,
    const float* __restrict__ W1, const float* __restrict__ b1,
    const float* __restrict__ W2, const float* __restrict__ b2,
    float* __restrict__ out)
{
    __shared__ __align__(16) short feat_s[NK * FSTRIDE];   // 32768 B
    __shared__ __align__(16) short h_s[64 * HSTRIDE];      // 33792 B

    const int t = threadIdx.x;          // 0..511
    const int wave = t >> 6;            // 0..7
    const int lane15 = t & 15;
    const int quad = (t >> 4) & 3;
    const int p = t & 255;              // pair id for features / staging
    const int half = t >> 8;            // 0/1: which half of features
    const int b = blockIdx.x >> 6;
    const int i0 = (blockIdx.x & 63) * ROWS_PER_BLK;

    // ---- k-row for pair j = p: block-invariant, cache in regs ----
    const float* kp = k + ((size_t)b * NK + p) * DIN;
    const float k0 = kp[0], k3 = kp[3], k4 = kp[4], k5 = kp[5], k6 = kp[6],
                k7 = kp[7], k8 = kp[8];
    const float k_speed = sqtf(k5 * k5 + k6 * k6);   // row-invariant

    // ---- W2 fragments in regs (GEMM2 B-operand), scaled by -ln2 ----
    bf16x8 w2f[8];
    if (wave < 4) {
#pragma unroll
        for (int ks = 0; ks < 8; ++ks) {
            const float* wp = W2 + (size_t)(ks * 32 + quad * 8) * NH + (lane15 & 7);
            bf16x8 v;
#pragma unroll
            for (int e = 0; e < 8; ++e)
                v[e] = f2bf(-0.69314718f * wp[(size_t)e * NH]);
            w2f[ks] = v;
        }
    }

    // ---- W1 fragments (A operand), scaled by -log2e ----
    const int n0 = wave * 32;
    bf16x8 w1f[2][2];
#pragma unroll
    for (int nt = 0; nt < 2; ++nt)
#pragma unroll
        for (int ks = 0; ks < 2; ++ks) {
            const float* wp = W1 + (size_t)(ks * 32 + quad * 8) * HIDDEN
                              + (n0 + nt * 16 + lane15);
            bf16x8 v;
#pragma unroll
            for (int e = 0; e < 8; ++e)
                v[e] = f2bf(-1.44269504f * wp[(size_t)e * HIDDEN]);
            w1f[nt][ks] = v;
        }
    // bias fragment (MFMA C-in at ks=0), scaled by -log2e
    f32x4 b1c[2];
#pragma unroll
    for (int nt = 0; nt < 2; ++nt) {
        float4 bb = *(const float4*)&b1[n0 + nt * 16 + quad * 4];
        b1c[nt] = (f32x4){-1.44269504f * bb.x, -1.44269504f * bb.y,
                          -1.44269504f * bb.z, -1.44269504f * bb.w};
    }
    const float b2v = (lane15 < NH) ? b2[lane15] : 0.f;
    // G2 output pointer base (valid only when lane15 < NH; never deref'd else)
    float* const outp = out + ((size_t)b * NH + (lane15 & 7)) * NQ * NK
                        + wave * 16 + quad * 4;

    const int sw = p & 7;        // feature-store swizzle
    const int swr = lane15 & 7;  // feat B-frag read swizzle
    const f32x2 one2 = {1.f, 1.f};

    // ================= row loop: 4 query rows =================
#pragma unroll 1
    for (int row = 0; row < ROWS_PER_BLK; ++row) {
        const int i = i0 + row;

        // ---- features for pair (i, j=p): proven math, 2 threads/pair ----
        {
            const float* qp = q + ((size_t)b * NQ + i) * DIN;
            const float q0 = qp[0], q3 = qp[3], q4 = qp[4], q5 = qp[5],
                        q6 = qp[6], q7 = qp[7], q8 = qp[8];

            const float dpx = k3 - q3, dpy = k4 - q4;
            const float dvx = k5 - q5, dvy = k6 - q6;
            const float dist = sqtf(dpx * dpx + dpy * dpy + 1e-6f);

            float feat[32];
            if (half == 0) {
                // c8 {0,1,6,7}: dist4 | inv_dist4 | ttca2+dist2 | team2+dspeed2
                const float inv_dist = rcpf(dist + 0.1f);
                const float dot_dp_dv = dpx * dvx + dpy * dvy;
                const float speed_sq = dvx * dvx + dvy * dvy;
                // tanh(relu(z)) = 1 - 2/(1 + 2^(2*log2e*z)), z >= 0
                const float z = fmaxf(0.f, -dot_dp_dv * rcpf(speed_sq + 1e-6f));
                const float ttca = 1.f - 2.f * rcpf(1.f + ex2f(2.88539008f * z));
                const float q_speed = sqtf(q5 * q5 + q6 * q6);
                const float delta_speed = k_speed - q_speed;
                four4(dist,     feat + 0);
                four4(inv_dist, feat + 8);
                four2(ttca,     feat + 16);
                feat[20] = feat[0]; feat[21] = feat[1];   // four2(dist) reuse
                feat[22] = feat[4]; feat[23] = feat[5];
                const bool st = (q0 == k0);               // same_team constants
                feat[24] = st ? 0.84147098f : 0.f;
                feat[25] = st ? 0.90929743f : 0.f;
                feat[26] = st ? 0.54030231f : 1.f;
                feat[27] = st ? -0.41614684f : 1.f;
                four2(delta_speed, feat + 28);
            } else {
                // c8 {2,3,4,5}: ata4 | aspect4 | dpx2+dpy2 | dvx2+dvy2
                const float inv_d2 = rcpf(dist + 1e-6f);
                const float bear_x = dpx * inv_d2, bear_y = dpy * inv_d2;
                const float ata = bear_x * q7 + bear_y * q8;
                const float aspect = bear_x * k7 + bear_y * k8;
                four4(ata,    feat + 0);
                four4(aspect, feat + 8);
                four2(dpx,    feat + 16);
                four2(dpy,    feat + 20);
                four2(dvx,    feat + 24);
                four2(dvy,    feat + 28);
            }
#pragma unroll
            for (int j = 0; j < 4; ++j) {
                const int c8 = half ? (j + 2) : (j < 2 ? j : j + 4);
                uint4 v;
                v.x = cvtpk(feat[j * 8 + 0], feat[j * 8 + 1]);
                v.y = cvtpk(feat[j * 8 + 2], feat[j * 8 + 3]);
                v.z = cvtpk(feat[j * 8 + 4], feat[j * 8 + 5]);
                v.w = cvtpk(feat[j * 8 + 6], feat[j * 8 + 7]);
                *(uint4*)&feat_s[p * FSTRIDE + ((c8 ^ sw) * 8)] = v;
            }
        }
        __syncthreads();  // feat_s(row) ready

        // ---- 4 chunks of 64 pairs ----
#pragma unroll 1
        for (int c = 0; c < 4; ++c) {
            const int p0 = c * 64;

            // GEMM1': bias rides as C-in on the ks=0 MFMAs
            f32x4 acc[2][4];
#pragma unroll
            for (int mt = 0; mt < 4; ++mt) {
                const int r2 = p0 + mt * 16 + lane15;
                const bf16x8 fb = *(const bf16x8*)
                    &feat_s[r2 * FSTRIDE + ((quad ^ swr) * 8)];
                acc[0][mt] = __builtin_amdgcn_mfma_f32_16x16x32_bf16(
                    w1f[0][0], fb, b1c[0], 0, 0, 0);
                acc[1][mt] = __builtin_amdgcn_mfma_f32_16x16x32_bf16(
                    w1f[1][0], fb, b1c[1], 0, 0, 0);
            }
#pragma unroll
            for (int mt = 0; mt < 4; ++mt) {
                const int r2 = p0 + mt * 16 + lane15;
                const bf16x8 fb = *(const bf16x8*)
                    &feat_s[r2 * FSTRIDE + (((4 + quad) ^ swr) * 8)];
#pragma unroll
                for (int nt = 0; nt < 2; ++nt)
                    acc[nt][mt] = __builtin_amdgcn_mfma_f32_16x16x32_bf16(
                        w1f[nt][1], fb, acc[nt][mt], 0, 0, 0);
            }

            // silu-COMPUTE into regs (no LDS): packed-f32 add/mul
            uint2 pk[2][4];
#pragma unroll
            for (int nt = 0; nt < 2; ++nt)
#pragma unroll
                for (int mt = 0; mt < 4; ++mt) {
                    const f32x4 a = acc[nt][mt];     // = -log2e * preact
                    const f32x2 a01 = {a[0], a[1]}, a23 = {a[2], a[3]};
                    const f32x2 e01 = {ex2f(a[0]), ex2f(a[1])};
                    const f32x2 e23 = {ex2f(a[2]), ex2f(a[3])};
                    const f32x2 t01 = e01 + one2;    // v_pk_add_f32
                    const f32x2 t23 = e23 + one2;
                    const f32x2 r01 = {rcpf(t01[0]), rcpf(t01[1])};
                    const f32x2 r23 = {rcpf(t23[0]), rcpf(t23[1])};
                    const f32x2 s01 = a01 * r01;     // v_pk_mul_f32
                    const f32x2 s23 = a23 * r23;     // = -1.4427*silu
                    pk[nt][mt].x = cvtpk(s01[0], s01[1]);
                    pk[nt][mt].y = cvtpk(s23[0], s23[1]);
                }

            __syncthreads();  // barrier#1: h_s(prev) fully consumed

            // only the 8 ds_write_b64 live between the barriers
#pragma unroll
            for (int nt = 0; nt < 2; ++nt)
#pragma unroll
                for (int mt = 0; mt < 4; ++mt) {
                    const int pair = mt * 16 + lane15;
                    const int hbase = n0 + nt * 16 + quad * 4;
                    *(uint2*)&h_s[pair * HSTRIDE + hbase] = pk[nt][mt];
                }
            __syncthreads();  // barrier#2: h_s(c) ready

            // GEMM2: waves 0-3, one 16-pair M-tile each; K=256; W2 in regs
            if (wave < 4) {
                const int pw = wave * 16;
                f32x4 acc2 = (f32x4){b2v, b2v, b2v, b2v};
#pragma unroll
                for (int ks = 0; ks < 8; ++ks) {
                    const bf16x8 ha = *(const bf16x8*)&h_s[(pw + lane15) * HSTRIDE
                                                            + ks * 32 + quad * 8];
                    acc2 = __builtin_amdgcn_mfma_f32_16x16x32_bf16(ha, w2f[ks], acc2, 0, 0, 0);
                }
                if (lane15 < NH) {
                    float* op = outp + (size_t)i * NK + p0;
                    *(float4*)op = make_float4(acc2[0], acc2[1], acc2[2], acc2[3]);
                }
            }
            // no end barrier: next chunk's GEMM1' touches only feat_s
        }
    }
}

extern "C" void kernel_launch(void* const* d_in, const int* in_sizes, int n_in,
                              void* d_out, int out_size, void* d_ws, size_t ws_size,
                              hipStream_t stream) {
    const float* q  = (const float*)d_in[0];
    const float* k  = (const float*)d_in[1];
    const float* W1 = (const float*)d_in[2];
    const float* b1 = (const float*)d_in[3];
    const float* W2 = (const float*)d_in[4];
    const float* b2 = (const float*)d_in[5];
    float* out = (float*)d_out;

    dim3 grid(NB * NQ / ROWS_PER_BLK);  // 512 blocks = 2/CU, one dispatch round
    dim3 block(512);                    // 8 waves: 16 waves/CU resident
    relfeat_mfma_kernel<<<grid, block, 0, stream>>>(q, k, W1, b1, W2, b2, out);
}